// Round 11
// baseline (202.460 us; speedup 1.0000x reference)
//
#include <hip/hip_runtime.h>

typedef unsigned short u16;
typedef unsigned int   u32;
typedef __attribute__((ext_vector_type(8))) short short8;
typedef __attribute__((ext_vector_type(4))) float f32x4;
typedef __attribute__((ext_vector_type(16))) float f32x16;
typedef __attribute__((ext_vector_type(4))) u32 u32x4;
typedef __attribute__((ext_vector_type(2))) u32 u32x2;
typedef __attribute__((ext_vector_type(2))) __bf16 bf16x2;

#define LAMBDA_INIT_F 0.78360576653162444f
#define SCALE_QK      0.17677669529663687f   // 1/sqrt(32)
#define LOG2E_F       1.4426950408889634f

// B=4 T=1024 E=1024 H=16 KVH=8 HD=32 DV=64 ; M = B*T = 4096

__device__ __forceinline__ u16 f2bf(float f) {
  u32 u = __float_as_uint(f);
  u32 r = (u + 0x7fffu + ((u >> 16) & 1u)) >> 16;
  return (u16)r;
}
__device__ __forceinline__ float bf2f(u16 h) {
  return __uint_as_float(((u32)h) << 16);
}
// pack 2 floats -> 1 u32 of 2 bf16 via native casts (compiler emits v_cvt_pk_bf16_f32)
__device__ __forceinline__ u32 pack2bf(float a, float b) {
  bf16x2 v; v[0] = (__bf16)a; v[1] = (__bf16)b;
  u32 w; __builtin_memcpy(&w, &v, 4); return w;
}
__device__ __forceinline__ void gload_lds16(const u16* g, u16* l) {
  __builtin_amdgcn_global_load_lds((const __attribute__((address_space(1))) u32*)g,
                                   (__attribute__((address_space(3))) u32*)l, 16, 0, 0);
}

// ---------------- prep kernels ----------------

__global__ void k_cvt_x(const float* __restrict__ x, u16* __restrict__ xb) {
  int id = blockIdx.x * 256 + threadIdx.x;
  float4 v = ((const float4*)x)[id];
  u16* o = xb + (size_t)id * 4;
  o[0] = f2bf(v.x); o[1] = f2bf(v.y); o[2] = f2bf(v.z); o[3] = f2bf(v.w);
}

// transpose fp32 KxN -> bf16 NxK (K=1024 always)
__global__ void k_transpose(const float* __restrict__ Wq, const float* __restrict__ Wk,
                            const float* __restrict__ Wv, const float* __restrict__ Wo,
                            u16* __restrict__ wt, u16* __restrict__ wot) {
  __shared__ float tile[32][33];
  const float* src; u16* dst; int N;
  switch (blockIdx.z) {
    case 0: src = Wq; dst = wt;               N = 1024; break;
    case 1: src = Wk; dst = wt + 1024 * 1024; N = 512;  break;
    case 2: src = Wv; dst = wt + 1536 * 1024; N = 512;  break;
    default: src = Wo; dst = wot;             N = 1024; break;
  }
  int nb = blockIdx.x * 32, kb = blockIdx.y * 32;
  if (nb >= N) return;
  int tx = threadIdx.x, ty = threadIdx.y;   // 32 x 8
  #pragma unroll
  for (int i = 0; i < 32; i += 8)
    tile[ty + i][tx] = src[(size_t)(kb + ty + i) * N + nb + tx];
  __syncthreads();
  #pragma unroll
  for (int i = 0; i < 32; i += 8)
    dst[(size_t)(nb + ty + i) * 1024 + kb + tx] = f2bf(tile[tx][ty + i]);
}

__global__ void k_rope_tab(float* __restrict__ cosT, float* __restrict__ sinT) {
  int id = blockIdx.x * 256 + threadIdx.x;   // 16384 = 1024*16
  if (id >= 16384) return;
  int t = id >> 4, i = id & 15;
  float inv = powf(10000.0f, -(float)i * (1.0f / 16.0f));
  float f = (float)t * inv;
  float sv, cv; sincosf(f, &sv, &cv);
  cosT[id] = cv; sinT[id] = sv;
}

// ---------------- GEMM: C[MxN] = A[MxK] * Bt[NxK]^T, bf16 in / fp32-or-bf16 out ----------------

template<int OBF16>
__global__ __launch_bounds__(256) void gemm_bt(const u16* __restrict__ A, const u16* __restrict__ Bt,
                                               void* __restrict__ Cv, int M, int N, int K, int ldc) {
  __shared__ u16 As[128 * 32];
  __shared__ u16 Bs[128 * 32];
  const int tid = threadIdx.x;
  const int wid = tid >> 6, lane = tid & 63;
  const int m0 = blockIdx.y * 128, n0 = blockIdx.x * 128;
  const int wr = wid >> 1, wc = wid & 1;
  f32x4 acc[4][4];
  #pragma unroll
  for (int m = 0; m < 4; ++m)
    #pragma unroll
    for (int n = 0; n < 4; ++n) acc[m][n] = (f32x4){0.f, 0.f, 0.f, 0.f};
  const int lrow = lane >> 2;
  const int lcol = (lane & 3) * 8;
  for (int k0 = 0; k0 < K; k0 += 32) {
    #pragma unroll
    for (int i = 0; i < 2; ++i) {
      const int ch = wid + i * 4;
      const int row = ch * 16 + lrow;
      gload_lds16(A  + (size_t)(m0 + row) * K + k0 + lcol, &As[ch * 512]);
      gload_lds16(Bt + (size_t)(n0 + row) * K + k0 + lcol, &Bs[ch * 512]);
    }
    __syncthreads();
    const int fr = lane & 15, fc = (lane >> 4) * 8;
    short8 af[4], bfr[4];
    #pragma unroll
    for (int m = 0; m < 4; ++m) af[m]  = *(const short8*)&As[(wr * 64 + m * 16 + fr) * 32 + fc];
    #pragma unroll
    for (int n = 0; n < 4; ++n) bfr[n] = *(const short8*)&Bs[(wc * 64 + n * 16 + fr) * 32 + fc];
    #pragma unroll
    for (int m = 0; m < 4; ++m)
      #pragma unroll
      for (int n = 0; n < 4; ++n)
        acc[m][n] = __builtin_amdgcn_mfma_f32_16x16x32_bf16(af[m], bfr[n], acc[m][n], 0, 0, 0);
    __syncthreads();
  }
  const int fr = lane & 15, fg = lane >> 4;
  #pragma unroll
  for (int m = 0; m < 4; ++m)
    #pragma unroll
    for (int n = 0; n < 4; ++n)
      #pragma unroll
      for (int r = 0; r < 4; ++r) {
        const int row = m0 + wr * 64 + m * 16 + fg * 4 + r;
        const int col = n0 + wc * 64 + n * 16 + fr;
        if (OBF16) ((u16*)Cv)[(size_t)row * ldc + col] = f2bf(acc[m][n][r]);
        else       ((float*)Cv)[(size_t)row * ldc + col] = acc[m][n][r];
      }
}

// ---------------- RoPE + head split/reorg ----------------
// qkvb bf16 [4096][2048]: cols 0..1023 Q (32 heads x 32), 1024..1535 K (16 x 32), 1536..2047 V (8 x 64)
// Q pre-scaled by log2(e)/sqrt(hd): softmax in attn runs in exp2 domain.

__global__ void k_rope_reorg(const u16* __restrict__ qkvb, const float* __restrict__ cosT,
                             const float* __restrict__ sinT,
                             u16* __restrict__ q1, u16* __restrict__ q2,
                             u16* __restrict__ k1, u16* __restrict__ k2) {
  int id = blockIdx.x * 256 + threadIdx.x;
  const int NQ = 4096 * 32 * 16;   // 2M rope pairs for Q
  const int NK = 4096 * 16 * 16;   // 1M rope pairs for K
  if (id < NQ) {
    int m = id >> 9, r = id & 511;
    int qh = r >> 4, d = r & 15;
    int b = m >> 10, t = m & 1023;
    float x1 = bf2f(qkvb[(size_t)m * 2048 + qh * 32 + d]);
    float x2 = bf2f(qkvb[(size_t)m * 2048 + qh * 32 + d + 16]);
    float c = cosT[t * 16 + d], s = sinT[t * 16 + d];
    const float SC = SCALE_QK * LOG2E_F;
    float o1 = (x1 * c + x2 * s) * SC, o2 = (x2 * c - x1 * s) * SC;
    int h = qh >> 1, comp = qh & 1;
    u16* dst = comp ? q2 : q1;
    size_t base = ((size_t)(b * 16 + h) * 1024 + t) * 32 + d;
    dst[base] = f2bf(o1); dst[base + 16] = f2bf(o2);
  } else if (id < NQ + NK) {
    int id2 = id - NQ;
    int m = id2 >> 8, r = id2 & 255;
    int kh = r >> 4, d = r & 15;
    int b = m >> 10, t = m & 1023;
    float x1 = bf2f(qkvb[(size_t)m * 2048 + 1024 + kh * 32 + d]);
    float x2 = bf2f(qkvb[(size_t)m * 2048 + 1024 + kh * 32 + d + 16]);
    float c = cosT[t * 16 + d], s = sinT[t * 16 + d];
    float o1 = x1 * c + x2 * s, o2 = x2 * c - x1 * s;
    int kvh = kh >> 1, comp = kh & 1;
    u16* dst = comp ? k2 : k1;
    size_t base = ((size_t)(b * 8 + kvh) * 1024 + t) * 32 + d;
    dst[base] = f2bf(o1); dst[base + 16] = f2bf(o2);
  }
}

// V transpose: qkvb V block [b][t][kvh*64+j] -> vt [b*8+kvh][j=64][t=1024] bf16
__global__ void k_vt(const u16* __restrict__ qkvb, u16* __restrict__ vt) {
  __shared__ u16 tile[32][34];
  int bh = blockIdx.z;
  int b = bh >> 3, kvh = bh & 7;
  int t0 = blockIdx.x * 32, j0 = blockIdx.y * 32;
  int tx = threadIdx.x, ty = threadIdx.y;   // 32 x 8
  const u16* src = qkvb + (size_t)b * 1024 * 2048 + 1536 + kvh * 64;
  #pragma unroll
  for (int i = 0; i < 32; i += 8)
    tile[ty + i][tx] = src[(size_t)(t0 + ty + i) * 2048 + j0 + tx];
  __syncthreads();
  u16* dst = vt + ((size_t)bh * 64 + j0) * 1024 + t0;
  #pragma unroll
  for (int i = 0; i < 32; i += 8)
    dst[(size_t)(ty + i) * 1024 + tx] = tile[tx][ty + i];
}

// ---------------- MFMA causal flash attention ----------------
// q1/q2: [B][H][T][32] bf16 (pre-scaled, exp2 domain) ; k1/k2: [B][KVH][T][32] ; vt: [B*KVH][64][T]
// out a1/a2: [B][T][H*64] bf16
// Swapped-operand scheme: S^T = mfma(K, Q) -> q on lane&31 ; O^T = mfma(Vt, P) -> q on lane&31.
// bid decode (bijection, output-identical): co-resident qb sets per CU sum to 36 tile-units.
// Causal-mask trigger must be R3's (kv0+63 > qbase+w*32) — qmaxw variant is the R4-R7 bug.
// VALU diet (R10): native cvt_pk bf16 pack, exp2-domain softmax, defer-max (THR=8), tree reductions.

#define KSTR 40   // K_lds row stride (u16), padded
#define VSTR 88   // Vt_lds row stride
#define PSTR 88   // P_lds row stride

__global__ __launch_bounds__(256) void attn_mfma(
    const u16* __restrict__ q1g, const u16* __restrict__ q2g,
    const u16* __restrict__ k1g, const u16* __restrict__ k2g,
    const u16* __restrict__ vtg,
    u16* __restrict__ a1, u16* __restrict__ a2) {
  __shared__ u16 Kl[64 * KSTR];
  __shared__ u16 Vl[64 * VSTR];
  __shared__ u16 Pl[4 * 32 * PSTR];

  const int bid = blockIdx.x;                 // 1024
  const int j = bid & 255, k = bid >> 8;
  const int prob = j >> 1;                    // 0..127
  const int qtab[2][4] = {{0, 7, 2, 5}, {6, 1, 4, 3}};
  const int qb = qtab[j & 1][k];
  const int comp = prob & 1, h = (prob >> 1) & 15, b = prob >> 5;
  const int tid = threadIdx.x;
  const int w = tid >> 6, lane = tid & 63;
  const int hi = lane >> 5, c = lane & 31;

  const u16* Qc  = (comp ? q2g : q1g) + (size_t)(b * 16 + h) * 1024 * 32;
  const u16* Kc  = (comp ? k2g : k1g) + (size_t)(b * 8 + (h >> 1)) * 1024 * 32;
  const u16* Vtc = vtg + (size_t)(b * 8 + (h >> 1)) * 64 * 1024;

  const int qbase = qb * 128;
  const int q = qbase + w * 32 + c;           // this lane's q column
  const int qmaxw = qbase + w * 32 + 31;

  // Q fragments, held in regs for the whole kernel
  short8 qf0 = *(const short8*)&Qc[(size_t)q * 32 + hi * 8];
  short8 qf1 = *(const short8*)&Qc[(size_t)q * 32 + 16 + hi * 8];

  f32x16 acc0, acc1;                          // O^T accumulators (dv tiles 0,1)
  #pragma unroll
  for (int r = 0; r < 16; ++r) { acc0[r] = 0.f; acc1[r] = 0.f; }
  float m_run = -1e30f, l_run = 0.f;

  const int ntiles = qb * 2 + 2;

  // staging assignments (256 threads)
  const int krow = tid >> 2, kseg = tid & 3;  // K tile: 64 rows x 64B
  const int vrow = tid >> 3, vseg = tid & 7;  // Vt tile: 64 rows x 128B (2 chunks)
  u32x4 kr, vr0, vr1;
  kr  = *(const u32x4*)&Kc[(size_t)krow * 32 + kseg * 8];
  vr0 = *(const u32x4*)&Vtc[(size_t)vrow * 1024 + vseg * 8];
  vr1 = *(const u32x4*)&Vtc[(size_t)(vrow + 32) * 1024 + vseg * 8];

  for (int t = 0; t < ntiles; ++t) {
    const int kv0 = t * 64;
    __syncthreads();                           // previous tile's readers done
    *(u32x4*)&Kl[krow * KSTR + kseg * 8] = kr;
    *(u32x4*)&Vl[vrow * VSTR + vseg * 8] = vr0;
    *(u32x4*)&Vl[(vrow + 32) * VSTR + vseg * 8] = vr1;
    __syncthreads();                           // tile ready
    if (t + 1 < ntiles) {
      const int kn = kv0 + 64;
      kr  = *(const u32x4*)&Kc[(size_t)(kn + krow) * 32 + kseg * 8];
      vr0 = *(const u32x4*)&Vtc[(size_t)vrow * 1024 + kn + vseg * 8];
      vr1 = *(const u32x4*)&Vtc[(size_t)(vrow + 32) * 1024 + kn + vseg * 8];
    }
    if (kv0 > qmaxw) continue;                 // fully masked for this wave

    // ---- QK^T (swapped): S^T[kv][q] ----
    f32x16 s0, s1;
    #pragma unroll
    for (int r = 0; r < 16; ++r) { s0[r] = 0.f; s1[r] = 0.f; }
    {
      short8 kf00 = *(const short8*)&Kl[c * KSTR + hi * 8];
      short8 kf01 = *(const short8*)&Kl[c * KSTR + 16 + hi * 8];
      short8 kf10 = *(const short8*)&Kl[(32 + c) * KSTR + hi * 8];
      short8 kf11 = *(const short8*)&Kl[(32 + c) * KSTR + 16 + hi * 8];
      s0 = __builtin_amdgcn_mfma_f32_32x32x16_bf16(kf00, qf0, s0, 0, 0, 0);
      s0 = __builtin_amdgcn_mfma_f32_32x32x16_bf16(kf01, qf1, s0, 0, 0, 0);
      s1 = __builtin_amdgcn_mfma_f32_32x32x16_bf16(kf10, qf0, s1, 0, 0, 0);
      s1 = __builtin_amdgcn_mfma_f32_32x32x16_bf16(kf11, qf1, s1, 0, 0, 0);
    }

    float sv[32];
    #pragma unroll
    for (int r = 0; r < 16; ++r) { sv[r] = s0[r]; sv[16 + r] = s1[r]; }

    // ---- causal mask (R3 condition: tile crosses smallest q in wave) ----
    if (kv0 + 63 > qbase + w * 32) {
      #pragma unroll
      for (int r = 0; r < 32; ++r) {
        int kv = kv0 + (r >> 4) * 32 + (r & 3) + 8 * ((r >> 2) & 3) + 4 * hi;
        if (kv > q) sv[r] = -1e30f;
      }
    }

    // ---- online softmax, exp2 domain (q lane-aligned; one cross-lane hop) ----
    float mx[16];
    #pragma unroll
    for (int r = 0; r < 16; ++r) mx[r] = fmaxf(sv[r], sv[16 + r]);
    #pragma unroll
    for (int sft = 8; sft >= 1; sft >>= 1)
      #pragma unroll
      for (int r = 0; r < sft; ++r) mx[r] = fmaxf(mx[r], mx[r + sft]);
    float mt = fmaxf(mx[0], __shfl_xor(mx[0], 32));
    if (!__all(mt <= m_run + 8.f)) {           // defer-max: rescale only on real growth
      float m_new = fmaxf(m_run, mt);
      float alpha = __builtin_amdgcn_exp2f(m_run - m_new);
      l_run *= alpha; m_run = m_new;
      #pragma unroll
      for (int r = 0; r < 16; ++r) { acc0[r] *= alpha; acc1[r] *= alpha; }
    }
    float ts[16];
    #pragma unroll
    for (int r = 0; r < 32; ++r) sv[r] = __builtin_amdgcn_exp2f(sv[r] - m_run);
    #pragma unroll
    for (int r = 0; r < 16; ++r) ts[r] = sv[r] + sv[16 + r];
    #pragma unroll
    for (int sft = 8; sft >= 1; sft >>= 1)
      #pragma unroll
      for (int r = 0; r < sft; ++r) ts[r] += ts[r + sft];
    l_run += ts[0] + __shfl_xor(ts[0], 32);

    // ---- pack P to bf16 (cvt_pk), write per-wave LDS [32 q][64 kv] ----
    u16* Pw = &Pl[(w * 32 + c) * PSTR];
    #pragma unroll
    for (int half = 0; half < 2; ++half)
      #pragma unroll
      for (int rr = 0; rr < 4; ++rr) {
        u32x2 wv;
        wv[0] = pack2bf(sv[half * 16 + rr * 4 + 0], sv[half * 16 + rr * 4 + 1]);
        wv[1] = pack2bf(sv[half * 16 + rr * 4 + 2], sv[half * 16 + rr * 4 + 3]);
        *(u32x2*)&Pw[half * 32 + rr * 8 + hi * 4] = wv;
      }

    // ---- PV: O^T[dv][q] += Vt * P ----
    const u16* Pr = &Pl[(w * 32 + c) * PSTR];
    #pragma unroll
    for (int kc = 0; kc < 4; ++kc) {
      short8 pf  = *(const short8*)&Pr[kc * 16 + hi * 8];
      short8 vf0 = *(const short8*)&Vl[c * VSTR + kc * 16 + hi * 8];
      short8 vf1 = *(const short8*)&Vl[(32 + c) * VSTR + kc * 16 + hi * 8];
      acc0 = __builtin_amdgcn_mfma_f32_32x32x16_bf16(vf0, pf, acc0, 0, 0, 0);
      acc1 = __builtin_amdgcn_mfma_f32_32x32x16_bf16(vf1, pf, acc1, 0, 0, 0);
    }
  }

  // ---- normalize + store O as bf16 (cvt_pk, 8B-granule coalesced) ----
  float inv = 1.f / l_run;
  u16* ao = (comp ? a2 : a1) + ((size_t)(b * 1024 + q)) * 1024 + h * 64;
  #pragma unroll
  for (int rr = 0; rr < 4; ++rr) {
    u32x2 w0, w1;
    w0[0] = pack2bf(acc0[rr * 4 + 0] * inv, acc0[rr * 4 + 1] * inv);
    w0[1] = pack2bf(acc0[rr * 4 + 2] * inv, acc0[rr * 4 + 3] * inv);
    w1[0] = pack2bf(acc1[rr * 4 + 0] * inv, acc1[rr * 4 + 1] * inv);
    w1[1] = pack2bf(acc1[rr * 4 + 2] * inv, acc1[rr * 4 + 3] * inv);
    *(u32x2*)&ao[rr * 8 + hi * 4] = w0;        // dv = 8rr + 4hi
    *(u32x2*)&ao[32 + rr * 8 + hi * 4] = w1;   // dv = 32 + 8rr + 4hi
  }
}

// ---------------- diff + RMS norm epilogue (bf16 in) -> bf16 A-matrix for GEMM2 ----------------

__global__ void k_diff_rms(const u16* __restrict__ a1, const u16* __restrict__ a2in,
                           const float* __restrict__ lq1, const float* __restrict__ lk1,
                           const float* __restrict__ lq2, const float* __restrict__ lk2,
                           const float* __restrict__ rmsw, u16* __restrict__ out) {
  int id = blockIdx.x * 256 + threadIdx.x;   // 65536 = 4096 rows * 16 heads
  if (id >= 65536) return;
  float s1 = 0.f, s2 = 0.f;
  #pragma unroll
  for (int i = 0; i < 32; ++i) { s1 += lq1[i] * lk1[i]; s2 += lq2[i] * lk2[i]; }
  float lam = __expf(s1) - __expf(s2) + LAMBDA_INIT_F;
  const u16* p1 = a1 + (size_t)id * 64;
  const u16* p2 = a2in + (size_t)id * 64;
  float yv[64]; float ss = 0.f;
  #pragma unroll
  for (int d8 = 0; d8 < 8; ++d8) {
    short8 v1 = *(const short8*)&p1[d8 * 8];
    short8 v2 = *(const short8*)&p2[d8 * 8];
    #pragma unroll
    for (int jj = 0; jj < 8; ++jj) {
      float v = bf2f((u16)v1[jj]) - lam * bf2f((u16)v2[jj]);
      yv[d8 * 8 + jj] = v; ss += v * v;
    }
  }
  float inv = rsqrtf(ss * (1.f / 64.f) + 1e-6f) * (1.f - LAMBDA_INIT_F);
  u16* o = out + (size_t)id * 64;
  #pragma unroll
  for (int d = 0; d < 64; ++d) o[d] = f2bf(yv[d] * inv * rmsw[d]);
}

// ---------------- launch ----------------

extern "C" void kernel_launch(void* const* d_in, const int* in_sizes, int n_in,
                              void* d_out, int out_size, void* d_ws, size_t ws_size,
                              hipStream_t stream) {
  (void)in_sizes; (void)n_in; (void)out_size; (void)ws_size;
  const float* x    = (const float*)d_in[0];
  const float* Wq   = (const float*)d_in[1];
  const float* Wk   = (const float*)d_in[2];
  const float* Wv   = (const float*)d_in[3];
  const float* Wo   = (const float*)d_in[4];
  const float* lq1  = (const float*)d_in[5];
  const float* lk1  = (const float*)d_in[6];
  const float* lq2  = (const float*)d_in[7];
  const float* lk2  = (const float*)d_in[8];
  const float* rmsw = (const float*)d_in[9];
  float* out = (float*)d_out;

  char* ws = (char*)d_ws;
  size_t off = 0;
  auto alloc = [&](size_t bytes) { void* p = ws + off; off += (bytes + 255) & ~(size_t)255; return p; };
  u16*   xb    = (u16*)  alloc(4096ULL * 1024 * 2);
  u16*   wt    = (u16*)  alloc(2048ULL * 1024 * 2);
  u16*   wot   = (u16*)  alloc(1024ULL * 1024 * 2);
  u16*   qkvb  = (u16*)  alloc(4096ULL * 2048 * 2);
  float* cosT  = (float*)alloc(16384ULL * 4);
  float* sinT  = (float*)alloc(16384ULL * 4);
  u16*   q1    = (u16*)  alloc(4ULL * 16 * 1024 * 32 * 2);
  u16*   q2    = (u16*)  alloc(4ULL * 16 * 1024 * 32 * 2);
  u16*   k1    = (u16*)  alloc(4ULL * 8 * 1024 * 32 * 2);
  u16*   k2    = (u16*)  alloc(4ULL * 8 * 1024 * 32 * 2);
  u16*   vt    = (u16*)  alloc(4ULL * 8 * 64 * 1024 * 2);
  u16*   a1    = (u16*)  alloc(4096ULL * 1024 * 2);
  u16*   a2    = (u16*)  alloc(4096ULL * 1024 * 2);
  u16*   am    = (u16*)  alloc(4096ULL * 1024 * 2);

  hipLaunchKernelGGL(k_cvt_x, dim3(4096), dim3(256), 0, stream, x, xb);
  hipLaunchKernelGGL(k_transpose, dim3(32, 32, 4), dim3(32, 8), 0, stream, Wq, Wk, Wv, Wo, wt, wot);
  hipLaunchKernelGGL(k_rope_tab, dim3(64), dim3(256), 0, stream, cosT, sinT);
  hipLaunchKernelGGL((gemm_bt<1>), dim3(16, 32), dim3(256), 0, stream, xb, wt, (void*)qkvb, 4096, 2048, 1024, 2048);
  hipLaunchKernelGGL(k_rope_reorg, dim3(12288), dim3(256), 0, stream, qkvb, cosT, sinT, q1, q2, k1, k2);
  hipLaunchKernelGGL(k_vt, dim3(32, 2, 32), dim3(32, 8), 0, stream, qkvb, vt);
  hipLaunchKernelGGL(attn_mfma, dim3(1024), dim3(256), 0, stream, q1, q2, k1, k2, vt, a1, a2);
  hipLaunchKernelGGL(k_diff_rms, dim3(256), dim3(256), 0, stream, a1, a2, lq1, lk1, lq2, lk2, rmsw, am);
  hipLaunchKernelGGL((gemm_bt<0>), dim3(8, 32), dim3(256), 0, stream, am, wot, (void*)out, 4096, 1024, 1024, 1024);
}

// Round 12
// 191.703 us; speedup vs baseline: 1.0561x; 1.0561x over previous
//
#include <hip/hip_runtime.h>

typedef unsigned short u16;
typedef unsigned int   u32;
typedef __attribute__((ext_vector_type(8))) short short8;
typedef __attribute__((ext_vector_type(4))) float f32x4;
typedef __attribute__((ext_vector_type(16))) float f32x16;
typedef __attribute__((ext_vector_type(4))) u32 u32x4;
typedef __attribute__((ext_vector_type(2))) u32 u32x2;
typedef __attribute__((ext_vector_type(2))) __bf16 bf16x2;

#define LAMBDA_INIT_F 0.78360576653162444f
#define SCALE_QK      0.17677669529663687f   // 1/sqrt(32)
#define LOG2E_F       1.4426950408889634f

// B=4 T=1024 E=1024 H=16 KVH=8 HD=32 DV=64 ; M = B*T = 4096

__device__ __forceinline__ u16 f2bf(float f) {
  u32 u = __float_as_uint(f);
  u32 r = (u + 0x7fffu + ((u >> 16) & 1u)) >> 16;
  return (u16)r;
}
__device__ __forceinline__ float bf2f(u16 h) {
  return __uint_as_float(((u32)h) << 16);
}
// pack 2 floats -> 1 u32 of 2 bf16 via native casts (compiler emits v_cvt_pk_bf16_f32)
__device__ __forceinline__ u32 pack2bf(float a, float b) {
  bf16x2 v; v[0] = (__bf16)a; v[1] = (__bf16)b;
  u32 w; __builtin_memcpy(&w, &v, 4); return w;
}
__device__ __forceinline__ void gload_lds16(const u16* g, u16* l) {
  __builtin_amdgcn_global_load_lds((const __attribute__((address_space(1))) u32*)g,
                                   (__attribute__((address_space(3))) u32*)l, 16, 0, 0);
}

// ---------------- prep kernels ----------------

__global__ void k_cvt_x(const float* __restrict__ x, u16* __restrict__ xb) {
  int id = blockIdx.x * 256 + threadIdx.x;
  float4 v = ((const float4*)x)[id];
  u16* o = xb + (size_t)id * 4;
  o[0] = f2bf(v.x); o[1] = f2bf(v.y); o[2] = f2bf(v.z); o[3] = f2bf(v.w);
}

// transpose fp32 KxN -> bf16 NxK (K=1024 always)
__global__ void k_transpose(const float* __restrict__ Wq, const float* __restrict__ Wk,
                            const float* __restrict__ Wv, const float* __restrict__ Wo,
                            u16* __restrict__ wt, u16* __restrict__ wot) {
  __shared__ float tile[32][33];
  const float* src; u16* dst; int N;
  switch (blockIdx.z) {
    case 0: src = Wq; dst = wt;               N = 1024; break;
    case 1: src = Wk; dst = wt + 1024 * 1024; N = 512;  break;
    case 2: src = Wv; dst = wt + 1536 * 1024; N = 512;  break;
    default: src = Wo; dst = wot;             N = 1024; break;
  }
  int nb = blockIdx.x * 32, kb = blockIdx.y * 32;
  if (nb >= N) return;
  int tx = threadIdx.x, ty = threadIdx.y;   // 32 x 8
  #pragma unroll
  for (int i = 0; i < 32; i += 8)
    tile[ty + i][tx] = src[(size_t)(kb + ty + i) * N + nb + tx];
  __syncthreads();
  #pragma unroll
  for (int i = 0; i < 32; i += 8)
    dst[(size_t)(nb + ty + i) * 1024 + kb + tx] = f2bf(tile[tx][ty + i]);
}

__global__ void k_rope_tab(float* __restrict__ cosT, float* __restrict__ sinT) {
  int id = blockIdx.x * 256 + threadIdx.x;   // 16384 = 1024*16
  if (id >= 16384) return;
  int t = id >> 4, i = id & 15;
  float inv = powf(10000.0f, -(float)i * (1.0f / 16.0f));
  float f = (float)t * inv;
  float sv, cv; sincosf(f, &sv, &cv);
  cosT[id] = cv; sinT[id] = sv;
}

// ---------------- GEMM: C[MxN] = A[MxK] * Bt[NxK]^T, bf16 in / fp32-or-bf16 out ----------------

template<int OBF16>
__global__ __launch_bounds__(256) void gemm_bt(const u16* __restrict__ A, const u16* __restrict__ Bt,
                                               void* __restrict__ Cv, int M, int N, int K, int ldc) {
  __shared__ u16 As[128 * 32];
  __shared__ u16 Bs[128 * 32];
  const int tid = threadIdx.x;
  const int wid = tid >> 6, lane = tid & 63;
  const int m0 = blockIdx.y * 128, n0 = blockIdx.x * 128;
  const int wr = wid >> 1, wc = wid & 1;
  f32x4 acc[4][4];
  #pragma unroll
  for (int m = 0; m < 4; ++m)
    #pragma unroll
    for (int n = 0; n < 4; ++n) acc[m][n] = (f32x4){0.f, 0.f, 0.f, 0.f};
  const int lrow = lane >> 2;
  const int lcol = (lane & 3) * 8;
  for (int k0 = 0; k0 < K; k0 += 32) {
    #pragma unroll
    for (int i = 0; i < 2; ++i) {
      const int ch = wid + i * 4;
      const int row = ch * 16 + lrow;
      gload_lds16(A  + (size_t)(m0 + row) * K + k0 + lcol, &As[ch * 512]);
      gload_lds16(Bt + (size_t)(n0 + row) * K + k0 + lcol, &Bs[ch * 512]);
    }
    __syncthreads();
    const int fr = lane & 15, fc = (lane >> 4) * 8;
    short8 af[4], bfr[4];
    #pragma unroll
    for (int m = 0; m < 4; ++m) af[m]  = *(const short8*)&As[(wr * 64 + m * 16 + fr) * 32 + fc];
    #pragma unroll
    for (int n = 0; n < 4; ++n) bfr[n] = *(const short8*)&Bs[(wc * 64 + n * 16 + fr) * 32 + fc];
    #pragma unroll
    for (int m = 0; m < 4; ++m)
      #pragma unroll
      for (int n = 0; n < 4; ++n)
        acc[m][n] = __builtin_amdgcn_mfma_f32_16x16x32_bf16(af[m], bfr[n], acc[m][n], 0, 0, 0);
    __syncthreads();
  }
  const int fr = lane & 15, fg = lane >> 4;
  #pragma unroll
  for (int m = 0; m < 4; ++m)
    #pragma unroll
    for (int n = 0; n < 4; ++n)
      #pragma unroll
      for (int r = 0; r < 4; ++r) {
        const int row = m0 + wr * 64 + m * 16 + fg * 4 + r;
        const int col = n0 + wc * 64 + n * 16 + fr;
        if (OBF16) ((u16*)Cv)[(size_t)row * ldc + col] = f2bf(acc[m][n][r]);
        else       ((float*)Cv)[(size_t)row * ldc + col] = acc[m][n][r];
      }
}

// ---------------- GEMM1 with fused RoPE epilogue ----------------
// C = xb @ [Wq|Wk|Wv]^T (M=4096, N=2048, K=1024).
// Epilogue: cols 0..1023 -> roped Q (pre-scaled by log2e/sqrt(hd)) into q1/q2;
//           cols 1024..1535 -> roped K into k1/k2; cols 1536..2047 -> bf16 V into qkvb.
// Fragment layout makes rope pairs lane-local: lane fr holds cols {colbase+n*16+fr},
// so (acc[m][0],acc[m][1]) = (x1,x2) of head colbase>>5 at d=fr, (acc[m][2],acc[m][3])
// the next head. Replaces the separate k_rope_reorg pass (rope now in fp32).

__global__ __launch_bounds__(256) void gemm_qkv(const u16* __restrict__ A, const u16* __restrict__ Bt,
                                                const float* __restrict__ cosT, const float* __restrict__ sinT,
                                                u16* __restrict__ q1, u16* __restrict__ q2,
                                                u16* __restrict__ k1, u16* __restrict__ k2,
                                                u16* __restrict__ qkvb) {
  const int K = 1024;
  __shared__ u16 As[128 * 32];
  __shared__ u16 Bs[128 * 32];
  const int tid = threadIdx.x;
  const int wid = tid >> 6, lane = tid & 63;
  const int m0 = blockIdx.y * 128, n0 = blockIdx.x * 128;
  const int wr = wid >> 1, wc = wid & 1;
  f32x4 acc[4][4];
  #pragma unroll
  for (int m = 0; m < 4; ++m)
    #pragma unroll
    for (int n = 0; n < 4; ++n) acc[m][n] = (f32x4){0.f, 0.f, 0.f, 0.f};
  const int lrow = lane >> 2;
  const int lcol = (lane & 3) * 8;
  for (int k0 = 0; k0 < K; k0 += 32) {
    #pragma unroll
    for (int i = 0; i < 2; ++i) {
      const int ch = wid + i * 4;
      const int row = ch * 16 + lrow;
      gload_lds16(A  + (size_t)(m0 + row) * K + k0 + lcol, &As[ch * 512]);
      gload_lds16(Bt + (size_t)(n0 + row) * K + k0 + lcol, &Bs[ch * 512]);
    }
    __syncthreads();
    const int fr = lane & 15, fc = (lane >> 4) * 8;
    short8 af[4], bfr[4];
    #pragma unroll
    for (int m = 0; m < 4; ++m) af[m]  = *(const short8*)&As[(wr * 64 + m * 16 + fr) * 32 + fc];
    #pragma unroll
    for (int n = 0; n < 4; ++n) bfr[n] = *(const short8*)&Bs[(wc * 64 + n * 16 + fr) * 32 + fc];
    #pragma unroll
    for (int m = 0; m < 4; ++m)
      #pragma unroll
      for (int n = 0; n < 4; ++n)
        acc[m][n] = __builtin_amdgcn_mfma_f32_16x16x32_bf16(af[m], bfr[n], acc[m][n], 0, 0, 0);
    __syncthreads();
  }
  const int fr = lane & 15, fg = lane >> 4;
  const int colbase = n0 + wc * 64;           // multiple of 64
  const int rowbase = m0 + wr * 64;
  if (colbase >= 1536) {
    // V: plain bf16 store into qkvb (k_vt reads this region)
    #pragma unroll
    for (int m = 0; m < 4; ++m)
      #pragma unroll
      for (int n = 0; n < 4; ++n)
        #pragma unroll
        for (int r = 0; r < 4; ++r) {
          const int row = rowbase + m * 16 + fg * 4 + r;
          const int col = colbase + n * 16 + fr;
          qkvb[(size_t)row * 2048 + col] = f2bf(acc[m][n][r]);
        }
  } else if (colbase >= 1024) {
    // K heads: kh0 = (colbase-1024)>>5 (even), pairs (n=0,1) and (n=2,3)
    const int kh0 = (colbase - 1024) >> 5;
    #pragma unroll
    for (int m = 0; m < 4; ++m)
      #pragma unroll
      for (int r = 0; r < 4; ++r) {
        const int row = rowbase + m * 16 + fg * 4 + r;
        const int b = row >> 10, t = row & 1023;
        const float c = cosT[t * 16 + fr], s = sinT[t * 16 + fr];
        #pragma unroll
        for (int hp = 0; hp < 2; ++hp) {
          const int kh = kh0 + hp;
          const float x1 = acc[m][hp * 2 + 0][r], x2 = acc[m][hp * 2 + 1][r];
          const float o1 = x1 * c + x2 * s, o2 = x2 * c - x1 * s;
          u16* dst = (kh & 1) ? k2 : k1;
          const size_t base = ((size_t)(b * 8 + (kh >> 1)) * 1024 + t) * 32 + fr;
          dst[base] = f2bf(o1); dst[base + 16] = f2bf(o2);
        }
      }
  } else {
    // Q heads: qh0 = colbase>>5 (even); scale by log2e/sqrt(hd) for exp2-domain attn
    const int qh0 = colbase >> 5;
    const float SC = SCALE_QK * LOG2E_F;
    #pragma unroll
    for (int m = 0; m < 4; ++m)
      #pragma unroll
      for (int r = 0; r < 4; ++r) {
        const int row = rowbase + m * 16 + fg * 4 + r;
        const int b = row >> 10, t = row & 1023;
        const float c = cosT[t * 16 + fr], s = sinT[t * 16 + fr];
        #pragma unroll
        for (int hp = 0; hp < 2; ++hp) {
          const int qh = qh0 + hp;
          const float x1 = acc[m][hp * 2 + 0][r], x2 = acc[m][hp * 2 + 1][r];
          const float o1 = (x1 * c + x2 * s) * SC, o2 = (x2 * c - x1 * s) * SC;
          u16* dst = (qh & 1) ? q2 : q1;
          const size_t base = ((size_t)(b * 16 + (qh >> 1)) * 1024 + t) * 32 + fr;
          dst[base] = f2bf(o1); dst[base + 16] = f2bf(o2);
        }
      }
  }
}

// V transpose: qkvb V block [b][t][kvh*64+j] -> vt [b*8+kvh][j=64][t=1024] bf16
__global__ void k_vt(const u16* __restrict__ qkvb, u16* __restrict__ vt) {
  __shared__ u16 tile[32][34];
  int bh = blockIdx.z;
  int b = bh >> 3, kvh = bh & 7;
  int t0 = blockIdx.x * 32, j0 = blockIdx.y * 32;
  int tx = threadIdx.x, ty = threadIdx.y;   // 32 x 8
  const u16* src = qkvb + (size_t)b * 1024 * 2048 + 1536 + kvh * 64;
  #pragma unroll
  for (int i = 0; i < 32; i += 8)
    tile[ty + i][tx] = src[(size_t)(t0 + ty + i) * 2048 + j0 + tx];
  __syncthreads();
  u16* dst = vt + ((size_t)bh * 64 + j0) * 1024 + t0;
  #pragma unroll
  for (int i = 0; i < 32; i += 8)
    dst[(size_t)(ty + i) * 1024 + tx] = tile[tx][ty + i];
}

// ---------------- MFMA causal flash attention ----------------
// q1/q2: [B][H][T][32] bf16 (pre-scaled, exp2 domain) ; k1/k2: [B][KVH][T][32] ; vt: [B*KVH][64][T]
// out a1/a2: [B][T][H*64] bf16
// Swapped-operand scheme: S^T = mfma(K, Q) -> q on lane&31 ; O^T = mfma(Vt, P) -> q on lane&31.
// bid decode (bijection, output-identical): co-resident qb sets per CU sum to 36 tile-units.
// Causal-mask trigger must be R3's (kv0+63 > qbase+w*32) — qmaxw variant is the R4-R7 bug.

#define KSTR 40   // K_lds row stride (u16), padded
#define VSTR 88   // Vt_lds row stride
#define PSTR 88   // P_lds row stride

__global__ __launch_bounds__(256) void attn_mfma(
    const u16* __restrict__ q1g, const u16* __restrict__ q2g,
    const u16* __restrict__ k1g, const u16* __restrict__ k2g,
    const u16* __restrict__ vtg,
    u16* __restrict__ a1, u16* __restrict__ a2) {
  __shared__ u16 Kl[64 * KSTR];
  __shared__ u16 Vl[64 * VSTR];
  __shared__ u16 Pl[4 * 32 * PSTR];

  const int bid = blockIdx.x;                 // 1024
  const int j = bid & 255, k = bid >> 8;
  const int prob = j >> 1;                    // 0..127
  const int qtab[2][4] = {{0, 7, 2, 5}, {6, 1, 4, 3}};
  const int qb = qtab[j & 1][k];
  const int comp = prob & 1, h = (prob >> 1) & 15, b = prob >> 5;
  const int tid = threadIdx.x;
  const int w = tid >> 6, lane = tid & 63;
  const int hi = lane >> 5, c = lane & 31;

  const u16* Qc  = (comp ? q2g : q1g) + (size_t)(b * 16 + h) * 1024 * 32;
  const u16* Kc  = (comp ? k2g : k1g) + (size_t)(b * 8 + (h >> 1)) * 1024 * 32;
  const u16* Vtc = vtg + (size_t)(b * 8 + (h >> 1)) * 64 * 1024;

  const int qbase = qb * 128;
  const int q = qbase + w * 32 + c;           // this lane's q column
  const int qmaxw = qbase + w * 32 + 31;

  // Q fragments, held in regs for the whole kernel
  short8 qf0 = *(const short8*)&Qc[(size_t)q * 32 + hi * 8];
  short8 qf1 = *(const short8*)&Qc[(size_t)q * 32 + 16 + hi * 8];

  f32x16 acc0, acc1;                          // O^T accumulators (dv tiles 0,1)
  #pragma unroll
  for (int r = 0; r < 16; ++r) { acc0[r] = 0.f; acc1[r] = 0.f; }
  float m_run = -1e30f, l_run = 0.f;

  const int ntiles = qb * 2 + 2;

  // staging assignments (256 threads)
  const int krow = tid >> 2, kseg = tid & 3;  // K tile: 64 rows x 64B
  const int vrow = tid >> 3, vseg = tid & 7;  // Vt tile: 64 rows x 128B (2 chunks)
  u32x4 kr, vr0, vr1;
  kr  = *(const u32x4*)&Kc[(size_t)krow * 32 + kseg * 8];
  vr0 = *(const u32x4*)&Vtc[(size_t)vrow * 1024 + vseg * 8];
  vr1 = *(const u32x4*)&Vtc[(size_t)(vrow + 32) * 1024 + vseg * 8];

  for (int t = 0; t < ntiles; ++t) {
    const int kv0 = t * 64;
    __syncthreads();                           // previous tile's readers done
    *(u32x4*)&Kl[krow * KSTR + kseg * 8] = kr;
    *(u32x4*)&Vl[vrow * VSTR + vseg * 8] = vr0;
    *(u32x4*)&Vl[(vrow + 32) * VSTR + vseg * 8] = vr1;
    __syncthreads();                           // tile ready
    if (t + 1 < ntiles) {
      const int kn = kv0 + 64;
      kr  = *(const u32x4*)&Kc[(size_t)(kn + krow) * 32 + kseg * 8];
      vr0 = *(const u32x4*)&Vtc[(size_t)vrow * 1024 + kn + vseg * 8];
      vr1 = *(const u32x4*)&Vtc[(size_t)(vrow + 32) * 1024 + kn + vseg * 8];
    }
    if (kv0 > qmaxw) continue;                 // fully masked for this wave

    // ---- QK^T (swapped): S^T[kv][q] ----
    f32x16 s0, s1;
    #pragma unroll
    for (int r = 0; r < 16; ++r) { s0[r] = 0.f; s1[r] = 0.f; }
    {
      short8 kf00 = *(const short8*)&Kl[c * KSTR + hi * 8];
      short8 kf01 = *(const short8*)&Kl[c * KSTR + 16 + hi * 8];
      short8 kf10 = *(const short8*)&Kl[(32 + c) * KSTR + hi * 8];
      short8 kf11 = *(const short8*)&Kl[(32 + c) * KSTR + 16 + hi * 8];
      s0 = __builtin_amdgcn_mfma_f32_32x32x16_bf16(kf00, qf0, s0, 0, 0, 0);
      s0 = __builtin_amdgcn_mfma_f32_32x32x16_bf16(kf01, qf1, s0, 0, 0, 0);
      s1 = __builtin_amdgcn_mfma_f32_32x32x16_bf16(kf10, qf0, s1, 0, 0, 0);
      s1 = __builtin_amdgcn_mfma_f32_32x32x16_bf16(kf11, qf1, s1, 0, 0, 0);
    }

    float sv[32];
    #pragma unroll
    for (int r = 0; r < 16; ++r) { sv[r] = s0[r]; sv[16 + r] = s1[r]; }

    // ---- causal mask (R3 condition: tile crosses smallest q in wave) ----
    if (kv0 + 63 > qbase + w * 32) {
      #pragma unroll
      for (int r = 0; r < 32; ++r) {
        int kv = kv0 + (r >> 4) * 32 + (r & 3) + 8 * ((r >> 2) & 3) + 4 * hi;
        if (kv > q) sv[r] = -1e30f;
      }
    }

    // ---- online softmax, exp2 domain (q lane-aligned; one cross-lane hop) ----
    float mx[16];
    #pragma unroll
    for (int r = 0; r < 16; ++r) mx[r] = fmaxf(sv[r], sv[16 + r]);
    #pragma unroll
    for (int sft = 8; sft >= 1; sft >>= 1)
      #pragma unroll
      for (int r = 0; r < sft; ++r) mx[r] = fmaxf(mx[r], mx[r + sft]);
    float mt = fmaxf(mx[0], __shfl_xor(mx[0], 32));
    if (!__all(mt <= m_run + 8.f)) {           // defer-max: rescale only on real growth
      float m_new = fmaxf(m_run, mt);
      float alpha = __builtin_amdgcn_exp2f(m_run - m_new);
      l_run *= alpha; m_run = m_new;
      #pragma unroll
      for (int r = 0; r < 16; ++r) { acc0[r] *= alpha; acc1[r] *= alpha; }
    }
    float ts[16];
    #pragma unroll
    for (int r = 0; r < 32; ++r) sv[r] = __builtin_amdgcn_exp2f(sv[r] - m_run);
    #pragma unroll
    for (int r = 0; r < 16; ++r) ts[r] = sv[r] + sv[16 + r];
    #pragma unroll
    for (int sft = 8; sft >= 1; sft >>= 1)
      #pragma unroll
      for (int r = 0; r < sft; ++r) ts[r] += ts[r + sft];
    l_run += ts[0] + __shfl_xor(ts[0], 32);

    // ---- pack P to bf16 (cvt_pk), write per-wave LDS [32 q][64 kv] ----
    u16* Pw = &Pl[(w * 32 + c) * PSTR];
    #pragma unroll
    for (int half = 0; half < 2; ++half)
      #pragma unroll
      for (int rr = 0; rr < 4; ++rr) {
        u32x2 wv;
        wv[0] = pack2bf(sv[half * 16 + rr * 4 + 0], sv[half * 16 + rr * 4 + 1]);
        wv[1] = pack2bf(sv[half * 16 + rr * 4 + 2], sv[half * 16 + rr * 4 + 3]);
        *(u32x2*)&Pw[half * 32 + rr * 8 + hi * 4] = wv;
      }

    // ---- PV: O^T[dv][q] += Vt * P ----
    const u16* Pr = &Pl[(w * 32 + c) * PSTR];
    #pragma unroll
    for (int kc = 0; kc < 4; ++kc) {
      short8 pf  = *(const short8*)&Pr[kc * 16 + hi * 8];
      short8 vf0 = *(const short8*)&Vl[c * VSTR + kc * 16 + hi * 8];
      short8 vf1 = *(const short8*)&Vl[(32 + c) * VSTR + kc * 16 + hi * 8];
      acc0 = __builtin_amdgcn_mfma_f32_32x32x16_bf16(vf0, pf, acc0, 0, 0, 0);
      acc1 = __builtin_amdgcn_mfma_f32_32x32x16_bf16(vf1, pf, acc1, 0, 0, 0);
    }
  }

  // ---- normalize + store O as bf16 (cvt_pk, 8B-granule coalesced) ----
  float inv = 1.f / l_run;
  u16* ao = (comp ? a2 : a1) + ((size_t)(b * 1024 + q)) * 1024 + h * 64;
  #pragma unroll
  for (int rr = 0; rr < 4; ++rr) {
    u32x2 w0, w1;
    w0[0] = pack2bf(acc0[rr * 4 + 0] * inv, acc0[rr * 4 + 1] * inv);
    w0[1] = pack2bf(acc0[rr * 4 + 2] * inv, acc0[rr * 4 + 3] * inv);
    w1[0] = pack2bf(acc1[rr * 4 + 0] * inv, acc1[rr * 4 + 1] * inv);
    w1[1] = pack2bf(acc1[rr * 4 + 2] * inv, acc1[rr * 4 + 3] * inv);
    *(u32x2*)&ao[rr * 8 + hi * 4] = w0;        // dv = 8rr + 4hi
    *(u32x2*)&ao[32 + rr * 8 + hi * 4] = w1;   // dv = 32 + 8rr + 4hi
  }
}

// ---------------- diff + RMS norm epilogue (bf16 in) -> bf16 A-matrix for GEMM2 ----------------

__global__ void k_diff_rms(const u16* __restrict__ a1, const u16* __restrict__ a2in,
                           const float* __restrict__ lq1, const float* __restrict__ lk1,
                           const float* __restrict__ lq2, const float* __restrict__ lk2,
                           const float* __restrict__ rmsw, u16* __restrict__ out) {
  int id = blockIdx.x * 256 + threadIdx.x;   // 65536 = 4096 rows * 16 heads
  if (id >= 65536) return;
  float s1 = 0.f, s2 = 0.f;
  #pragma unroll
  for (int i = 0; i < 32; ++i) { s1 += lq1[i] * lk1[i]; s2 += lq2[i] * lk2[i]; }
  float lam = __expf(s1) - __expf(s2) + LAMBDA_INIT_F;
  const u16* p1 = a1 + (size_t)id * 64;
  const u16* p2 = a2in + (size_t)id * 64;
  float yv[64]; float ss = 0.f;
  #pragma unroll
  for (int d8 = 0; d8 < 8; ++d8) {
    short8 v1 = *(const short8*)&p1[d8 * 8];
    short8 v2 = *(const short8*)&p2[d8 * 8];
    #pragma unroll
    for (int jj = 0; jj < 8; ++jj) {
      float v = bf2f((u16)v1[jj]) - lam * bf2f((u16)v2[jj]);
      yv[d8 * 8 + jj] = v; ss += v * v;
    }
  }
  float inv = rsqrtf(ss * (1.f / 64.f) + 1e-6f) * (1.f - LAMBDA_INIT_F);
  u16* o = out + (size_t)id * 64;
  #pragma unroll
  for (int d = 0; d < 64; ++d) o[d] = f2bf(yv[d] * inv * rmsw[d]);
}

// ---------------- launch ----------------

extern "C" void kernel_launch(void* const* d_in, const int* in_sizes, int n_in,
                              void* d_out, int out_size, void* d_ws, size_t ws_size,
                              hipStream_t stream) {
  (void)in_sizes; (void)n_in; (void)out_size; (void)ws_size;
  const float* x    = (const float*)d_in[0];
  const float* Wq   = (const float*)d_in[1];
  const float* Wk   = (const float*)d_in[2];
  const float* Wv   = (const float*)d_in[3];
  const float* Wo   = (const float*)d_in[4];
  const float* lq1  = (const float*)d_in[5];
  const float* lk1  = (const float*)d_in[6];
  const float* lq2  = (const float*)d_in[7];
  const float* lk2  = (const float*)d_in[8];
  const float* rmsw = (const float*)d_in[9];
  float* out = (float*)d_out;

  char* ws = (char*)d_ws;
  size_t off = 0;
  auto alloc = [&](size_t bytes) { void* p = ws + off; off += (bytes + 255) & ~(size_t)255; return p; };
  u16*   xb    = (u16*)  alloc(4096ULL * 1024 * 2);
  u16*   wt    = (u16*)  alloc(2048ULL * 1024 * 2);
  u16*   wot   = (u16*)  alloc(1024ULL * 1024 * 2);
  u16*   qkvb  = (u16*)  alloc(4096ULL * 2048 * 2);
  float* cosT  = (float*)alloc(16384ULL * 4);
  float* sinT  = (float*)alloc(16384ULL * 4);
  u16*   q1    = (u16*)  alloc(4ULL * 16 * 1024 * 32 * 2);
  u16*   q2    = (u16*)  alloc(4ULL * 16 * 1024 * 32 * 2);
  u16*   k1    = (u16*)  alloc(4ULL * 8 * 1024 * 32 * 2);
  u16*   k2    = (u16*)  alloc(4ULL * 8 * 1024 * 32 * 2);
  u16*   vt    = (u16*)  alloc(4ULL * 8 * 64 * 1024 * 2);
  u16*   a1    = (u16*)  alloc(4096ULL * 1024 * 2);
  u16*   a2    = (u16*)  alloc(4096ULL * 1024 * 2);
  u16*   am    = (u16*)  alloc(4096ULL * 1024 * 2);

  hipLaunchKernelGGL(k_cvt_x, dim3(4096), dim3(256), 0, stream, x, xb);
  hipLaunchKernelGGL(k_transpose, dim3(32, 32, 4), dim3(32, 8), 0, stream, Wq, Wk, Wv, Wo, wt, wot);
  hipLaunchKernelGGL(k_rope_tab, dim3(64), dim3(256), 0, stream, cosT, sinT);
  hipLaunchKernelGGL(gemm_qkv, dim3(16, 32), dim3(256), 0, stream, xb, wt, cosT, sinT,
                     q1, q2, k1, k2, qkvb);
  hipLaunchKernelGGL(k_vt, dim3(32, 2, 32), dim3(32, 8), 0, stream, qkvb, vt);
  hipLaunchKernelGGL(attn_mfma, dim3(1024), dim3(256), 0, stream, q1, q2, k1, k2, vt, a1, a2);
  hipLaunchKernelGGL(k_diff_rms, dim3(256), dim3(256), 0, stream, a1, a2, lq1, lk1, lq2, lk2, rmsw, am);
  hipLaunchKernelGGL((gemm_bt<0>), dim3(8, 32), dim3(256), 0, stream, am, wot, (void*)out, 4096, 1024, 1024, 1024);
}